// Round 2
// 231.057 us; speedup vs baseline: 1.0420x; 1.0420x over previous
//
#include <hip/hip_runtime.h>
#include <hip/hip_bf16.h>
#include <stdint.h>

// MultiheadSelfAttention: B=2, S=4096, D=512, H=8, HD=64
// v11b: same as v11 (P-transpose eliminated via 16x16x16 PV MFMA whose
// B-operand layout equals the QK^T C-layout k-grouping), with a HARDENED
// MFMA16 dispatch: builtin _1k spelling -> alt spelling -> inline asm
// (v_mfma_f32_16x16x16_bf16 is valid gfx950 per ISA ref §10).
// GEMMs unchanged from v8/v9/v10.

typedef __attribute__((ext_vector_type(8))) short short8;
typedef __attribute__((ext_vector_type(4))) short sv4;
typedef __attribute__((ext_vector_type(4))) float floatx4;

#define MFMA(a, b, c) __builtin_amdgcn_mfma_f32_16x16x32_bf16((a), (b), (c), 0, 0, 0)

__device__ __forceinline__ floatx4 MFMA16(sv4 a, sv4 b, floatx4 c) {
#if __has_builtin(__builtin_amdgcn_mfma_f32_16x16x16bf16_1k)
    return __builtin_amdgcn_mfma_f32_16x16x16bf16_1k(a, b, c, 0, 0, 0);
#elif __has_builtin(__builtin_amdgcn_mfma_f32_16x16x16_bf16)
    return __builtin_amdgcn_mfma_f32_16x16x16_bf16(a, b, c, 0, 0, 0);
#else
    floatx4 d;
    asm volatile("v_mfma_f32_16x16x16_bf16 %0, %1, %2, %3"
                 : "=v"(d) : "v"(a), "v"(b), "v"(c));
    return d;
#endif
}

typedef __attribute__((address_space(1))) const void* gas_t;
typedef __attribute__((address_space(3))) void* las_t;
#define GLDS16(g, l) __builtin_amdgcn_global_load_lds((gas_t)(g), (las_t)(l), 16, 0, 0)

#define SM_SHIFT 13.0f

__device__ __forceinline__ short f2bf(float f) {
    union { float f; uint32_t u; } c; c.f = f;
    uint32_t u = c.u;
    u += 0x7fffu + ((u >> 16) & 1u);   // RNE
    return (short)(u >> 16);
}
__device__ __forceinline__ float bf2f(short s) {
    union { float f; uint32_t u; } c; c.u = ((uint32_t)(uint16_t)s) << 16;
    return c.f;
}
__device__ __forceinline__ int pack2(float a, float b) {
    return (int)(uint16_t)f2bf(a) | ((int)(uint16_t)f2bf(b) << 16);
}
// bf16 pack of two floats: 1 instr on gfx950 if builtin exists, else 3.
__device__ __forceinline__ int pack2rn(float a, float b) {
#if __has_builtin(__builtin_amdgcn_cvt_pk_bf16_f32)
    auto r = __builtin_amdgcn_cvt_pk_bf16_f32(a, b);
    int out; __builtin_memcpy(&out, &r, 4);
    return out;
#else
    union { float f; uint32_t u; } x, y; x.f = a; y.f = b;
    return __builtin_amdgcn_perm(y.u + 0x8000u, x.u + 0x8000u, 0x07060302);
#endif
}

// ---------------------------------------------------------------- converts
__global__ void cvt_bf16(const float* __restrict__ src, short* __restrict__ dst, int n) {
    int i = (blockIdx.x * 256 + threadIdx.x) * 8;
    if (i >= n) return;
    floatx4 v0 = *(const floatx4*)(src + i);
    floatx4 v1 = *(const floatx4*)(src + i + 4);
    short8 o;
    #pragma unroll
    for (int j = 0; j < 4; ++j) { o[j] = f2bf(v0[j]); o[4 + j] = f2bf(v1[j]); }
    *(short8*)(dst + i) = o;
}

__global__ void cvt3_bf16(const float* __restrict__ s0, const float* __restrict__ s1,
                          const float* __restrict__ s2, short* __restrict__ d0,
                          short* __restrict__ d1, short* __restrict__ d2) {
    int idx = blockIdx.x * 256 + threadIdx.x;
    int which = idx >> 15;
    int i = (idx & 32767) * 8;
    const float* src = which == 0 ? s0 : which == 1 ? s1 : s2;
    short* dst = which == 0 ? d0 : which == 1 ? d1 : d2;
    floatx4 v0 = *(const floatx4*)(src + i);
    floatx4 v1 = *(const floatx4*)(src + i + 4);
    short8 o;
    #pragma unroll
    for (int j = 0; j < 4; ++j) { o[j] = f2bf(v0[j]); o[4 + j] = f2bf(v1[j]); }
    *(short8*)(dst + i) = o;
}

__global__ void cvt_split(const float* __restrict__ src, short* __restrict__ hi,
                          short* __restrict__ lo, int n) {
    int i = (blockIdx.x * 256 + threadIdx.x) * 8;
    if (i >= n) return;
    floatx4 v0 = *(const floatx4*)(src + i);
    floatx4 v1 = *(const floatx4*)(src + i + 4);
    short8 h, l;
    #pragma unroll
    for (int j = 0; j < 4; ++j) {
        short hh = f2bf(v0[j]); h[j] = hh; l[j] = f2bf(v0[j] - bf2f(hh));
        short hh1 = f2bf(v1[j]); h[4 + j] = hh1; l[4 + j] = f2bf(v1[j] - bf2f(hh1));
    }
    *(short8*)(hi + i) = h;
    *(short8*)(lo + i) = l;
}

// ---------------------------------------------------------------- QKV GEMM
__global__ __launch_bounds__(256) void qkv_gemm(
    const short* __restrict__ Xb,
    const short* __restrict__ Wq, const short* __restrict__ Wk, const short* __restrict__ Wv,
    const float* __restrict__ bq, const float* __restrict__ bk, const float* __restrict__ bv,
    short* __restrict__ Qo, short* __restrict__ Ko, short* __restrict__ VTo)
{
    __shared__ short SMEM[16384];                 // 32 KB
    #define ASH(bf) (SMEM + (bf) * 4096)
    #define BSH(bf) (SMEM + 8192 + (bf) * 4096)
    const int lane = threadIdx.x & 63, wave = threadIdx.x >> 6;
    const int col = lane & 15, quad = lane >> 4;
    const int wm = wave & 1, wn = wave >> 1;
    const int m0 = blockIdx.x * 128;
    const int by = blockIdx.y;
    const int which = by >> 2;                    // 0=Q,1=K,2=V
    const int n0 = (by & 3) * 128;
    const short* W = which == 0 ? Wq : which == 1 ? Wk : Wv;
    const float* bias = which == 0 ? bq : which == 1 ? bk : bv;
    const float oscale = which == 0 ? 0.1803368801111204f : 1.0f;  // 0.125*log2e

    const int rl = lane >> 2, pch = lane & 3;
    const int lch = pch ^ (rl & 3) ^ ((rl >> 2) & 3);
    const int seg = wave * 2;
    const short* ag0 = Xb + (size_t)(m0 + seg * 16 + rl) * 512 + lch * 8;
    const short* ag1 = ag0 + (size_t)16 * 512;
    const short* bg0 = W + (size_t)(n0 + seg * 16 + rl) * 512 + lch * 8;
    const short* bg1 = bg0 + (size_t)16 * 512;

    floatx4 acc[4][4] = {};

    GLDS16(ag0, ASH(0) + seg * 512);
    GLDS16(ag1, ASH(0) + (seg + 1) * 512);
    GLDS16(bg0, BSH(0) + seg * 512);
    GLDS16(bg1, BSH(0) + (seg + 1) * 512);
    __syncthreads();

    for (int t = 0; t < 16; ++t) {
        const int cur = t & 1;
        if (t < 15) {
            const int kb = (t + 1) * 32;
            GLDS16(ag0 + kb, ASH(cur ^ 1) + seg * 512);
            GLDS16(ag1 + kb, ASH(cur ^ 1) + (seg + 1) * 512);
            GLDS16(bg0 + kb, BSH(cur ^ 1) + seg * 512);
            GLDS16(bg1 + kb, BSH(cur ^ 1) + (seg + 1) * 512);
        }
        short8 af[4], bf[4];
        #pragma unroll
        for (int it = 0; it < 4; ++it) {
            const int rA = wm * 64 + it * 16 + col;
            const int pA = quad ^ (rA & 3) ^ ((rA >> 2) & 3);
            af[it] = *(const short8*)(ASH(cur) + rA * 32 + pA * 8);
            const int rB = wn * 64 + it * 16 + col;
            const int pB = quad ^ (rB & 3) ^ ((rB >> 2) & 3);
            bf[it] = *(const short8*)(BSH(cur) + rB * 32 + pB * 8);
        }
        #pragma unroll
        for (int i = 0; i < 4; ++i)
            #pragma unroll
            for (int j = 0; j < 4; ++j)
                acc[i][j] = MFMA(af[i], bf[j], acc[i][j]);
        __syncthreads();
    }

    if (which < 2) {
        #pragma unroll
        for (int i = 0; i < 4; ++i)
            #pragma unroll
            for (int j = 0; j < 4; ++j)
                #pragma unroll
                for (int r = 0; r < 4; ++r) {
                    int m = m0 + wm * 64 + i * 16 + quad * 4 + r;
                    int n = n0 + wn * 64 + j * 16 + col;
                    float v = (acc[i][j][r] + bias[n]) * oscale;
                    int b = m >> 12, s = m & 4095;
                    int h = n >> 6, hd = n & 63;
                    int bh = b * 8 + h;
                    short bv16 = f2bf(v);
                    if (which == 0) Qo[((size_t)bh * 4096 + s) * 64 + hd] = bv16;
                    else            Ko[((size_t)bh * 4096 + s) * 64 + hd] = bv16;
                }
    } else {
        // V: per-wave LDS transpose (post-barrier, staging LDS is dead)
        short* tb = SMEM + wave * 4096;
        #pragma unroll
        for (int n2 = 0; n2 < 2; ++n2) {
            #pragma unroll
            for (int jj = 0; jj < 2; ++jj) {
                const int j = n2 * 2 + jj;
                const int n_rel = jj * 16 + col;
                const float bv_ = bias[n0 + wn * 64 + j * 16 + col];
                #pragma unroll
                for (int i = 0; i < 4; ++i) {
                    const int m_rel = i * 16 + quad * 4;
                    *(int*)(tb + n_rel * 72 + m_rel) =
                        pack2(acc[i][j][0] + bv_, acc[i][j][1] + bv_);
                    *(int*)(tb + n_rel * 72 + m_rel + 2) =
                        pack2(acc[i][j][2] + bv_, acc[i][j][3] + bv_);
                }
            }
            asm volatile("s_waitcnt lgkmcnt(0)" ::: "memory");  // wave-local
            const int n_rel = lane & 31, half = lane >> 5;
            const int n = n0 + wn * 64 + n2 * 32 + n_rel;
            const int h = n >> 6, hd = n & 63;
            const int bh = (m0 >> 12) * 8 + h;
            const int s0 = (m0 & 4095) + wm * 64 + half * 32;
            const short* src = tb + n_rel * 72 + half * 32;
            short* dst = VTo + ((size_t)bh * 64 + hd) * 4096 + s0;
            #pragma unroll
            for (int c = 0; c < 4; ++c)
                *(int4*)(dst + c * 8) = *(const int4*)(src + c * 8);
        }
    }
    #undef ASH
    #undef BSH
}

// ---------------------------------------------------------------- flash attn
// Fixed-shift softmax; shift pre-folded into sa (QK^T seeded with C=-13).
// P packed to bf16 pairs feeds the 16x16x16 PV MFMA's B-operand DIRECTLY
// (both use k = quad*4+j grouping) -- no lane exchange. l accumulated via
// ones-MFMA on the same fragments.
__device__ __forceinline__ void softmax_pk(
    const floatx4* sa, floatx4& lacc, sv4 ones1, sv4* pb)
{
    #pragma unroll
    for (int nt = 0; nt < 4; ++nt) {
        float p0 = exp2f(sa[nt][0]);
        float p1 = exp2f(sa[nt][1]);
        float p2 = exp2f(sa[nt][2]);
        float p3 = exp2f(sa[nt][3]);
        union { int i[2]; sv4 s; } u;
        u.i[0] = pack2rn(p0, p1);
        u.i[1] = pack2rn(p2, p3);
        pb[nt] = u.s;
        lacc = MFMA16(ones1, u.s, lacc);   // l += column sums of this 16-k block
    }
}

__global__ __launch_bounds__(512, 4) void flash_attn(
    const short* __restrict__ Q, const short* __restrict__ Kk,
    const short* __restrict__ VT,
    short* __restrict__ Ahi, short* __restrict__ Alo)
{
    __shared__ float SMEMf[16384];               // 64 KB
    short* SMEM = (short*)SMEMf;
    const int lane = threadIdx.x & 63, wave = threadIdx.x >> 6;
    const int col = lane & 15, quad = lane >> 4;
    const int id = blockIdx.x;
    const int bh = (id & 7) * 2 + (id >> 8);     // 2 bh per XCD cluster
    const int bx = (id >> 3) & 31;
    const int b = bh >> 3, h = bh & 7;
    const int qw = wave & 3, kz = wave >> 2;
    const int q0 = bx * 128 + qw * 32;
    const int kbeg = kz * 2048;
    const size_t base = (size_t)bh * 4096 * 64;
    const size_t vbase = (size_t)bh * 64 * 4096;

    #define KOFF(z, f) (((z) * 2 + (f)) * 4096)
    #define VOFF(z, f) (16384 + ((z) * 2 + (f)) * 4096)

    const short* qptr = Q + base + (size_t)(q0 + col) * 64 + quad * 8;
    short8 qA0 = *(const short8*)(qptr);
    short8 qA1 = *(const short8*)(qptr + 32);
    short8 qB0 = *(const short8*)(qptr + 16 * 64);
    short8 qB1 = *(const short8*)(qptr + 16 * 64 + 32);

    const int rloc = lane >> 3, pch = lane & 7;
    const int lch = pch ^ rloc;
    const short* kst0 = Kk + base + (size_t)(kbeg + qw * 16 + rloc) * 64 + lch * 8;
    const short* kst1 = kst0 + (size_t)8 * 64;
    const short* vst0 = VT + vbase + (size_t)(qw * 16 + rloc) * 4096 + kbeg + lch * 8;
    const short* vst1 = vst0 + (size_t)8 * 4096;

    floatx4 oA[4] = {}, oB[4] = {};
    floatx4 laccA = {0.f, 0.f, 0.f, 0.f}, laccB = {0.f, 0.f, 0.f, 0.f};
    const floatx4 mshift = {-SM_SHIFT, -SM_SHIFT, -SM_SHIFT, -SM_SHIFT};
    sv4 ones1;
    #pragma unroll
    for (int j = 0; j < 4; ++j) ones1[j] = (short)0x3F80;   // bf16 1.0

    const int sw = col & 7;
    const int co0 = (quad ^ sw) * 8;
    const int co1 = ((quad + 4) ^ sw) * 8;
    // V fragment offsets for 16x16x16 PV: logical elem = nt*16 + quad*4;
    // 16B-chunk swizzle c_phys = c_log ^ (row&7), row&7 == col&7 == sw.
    int voff[4];
    #pragma unroll
    for (int nt = 0; nt < 4; ++nt)
        voff[nt] = ((2 * nt + (quad >> 1)) ^ sw) * 8 + (quad & 1) * 4;

    {
        short* kl = SMEM + KOFF(kz, 0) + (qw * 16) * 64;
        short* vl = SMEM + VOFF(kz, 0) + (qw * 16) * 64;
        GLDS16(kst0, kl);
        GLDS16(kst1, kl + 8 * 64);
        GLDS16(vst0, vl);
        GLDS16(vst1, vl + 8 * 64);
    }
    __syncthreads();

    for (int t = 0; t < 32; ++t) {
        const int cur = t & 1;
        if (t < 31) {
            const int kk2 = (t + 1) * 64;
            short* kl = SMEM + KOFF(kz, cur ^ 1) + (qw * 16) * 64;
            short* vl = SMEM + VOFF(kz, cur ^ 1) + (qw * 16) * 64;
            GLDS16(kst0 + (size_t)kk2 * 64, kl);
            GLDS16(kst1 + (size_t)kk2 * 64, kl + 8 * 64);
            GLDS16(vst0 + kk2, vl);
            GLDS16(vst1 + kk2, vl + 8 * 64);
        }
        floatx4 saA[4], saB[4];
        #pragma unroll
        for (int nt = 0; nt < 4; ++nt) {
            const short* kr = SMEM + KOFF(kz, cur) + (nt * 16 + col) * 64;
            short8 k0 = *(const short8*)(kr + co0);
            short8 k1 = *(const short8*)(kr + co1);
            floatx4 z = MFMA(k0, qA0, mshift);       // seed C=-13: sa = S~ - 13
            saA[nt] = MFMA(k1, qA1, z);
            floatx4 z2 = MFMA(k0, qB0, mshift);
            saB[nt] = MFMA(k1, qB1, z2);
        }
        sv4 pbA[4], pbB[4];
        softmax_pk(saA, laccA, ones1, pbA);
        softmax_pk(saB, laccB, ones1, pbB);
        #pragma unroll
        for (int mt = 0; mt < 4; ++mt) {
            const short* vr = SMEM + VOFF(kz, cur) + (mt * 16 + col) * 64;
            #pragma unroll
            for (int nt = 0; nt < 4; ++nt) {
                const sv4 v = *(const sv4*)(vr + voff[nt]);
                oA[mt] = MFMA16(v, pbA[nt], oA[mt]);
                oB[mt] = MFMA16(v, pbB[nt], oB[mt]);
            }
        }
        __syncthreads();
    }

    float lA = laccA[0], lB = laccB[0];   // quad-uniform (full chunk sums)

    // ---- split-K merge: same fixed shift on both halves -> pure add
    float* Osh = SMEMf;
    float* Msh = SMEMf + 8704;   // reused for l
    if (kz == 1) {
        #pragma unroll
        for (int mt = 0; mt < 4; ++mt) {
            *(floatx4*)&Osh[(qw * 2 + 0) * 1088 + col * 68 + mt * 16 + quad * 4] = oA[mt];
            *(floatx4*)&Osh[(qw * 2 + 1) * 1088 + col * 68 + mt * 16 + quad * 4] = oB[mt];
        }
        if (quad == 0) {
            Msh[qw * 32 + col] = lA;
            Msh[qw * 32 + col + 16] = lB;
        }
    }
    __syncthreads();
    if (kz == 0) {
        float linvA = 1.0f / (lA + Msh[qw * 32 + col]);
        float linvB = 1.0f / (lB + Msh[qw * 32 + col + 16]);
        size_t rowA = (size_t)(b * 4096 + q0 + col) * 512 + h * 64;
        size_t rowB = rowA + (size_t)16 * 512;
        #pragma unroll
        for (int mt = 0; mt < 4; ++mt) {
            floatx4 o2A = *(const floatx4*)&Osh[(qw * 2 + 0) * 1088 + col * 68 + mt * 16 + quad * 4];
            floatx4 o2B = *(const floatx4*)&Osh[(qw * 2 + 1) * 1088 + col * 68 + mt * 16 + quad * 4];
            float w0 = (oA[mt][0] + o2A[0]) * linvA;
            float w1 = (oA[mt][1] + o2A[1]) * linvA;
            float w2 = (oA[mt][2] + o2A[2]) * linvA;
            float w3 = (oA[mt][3] + o2A[3]) * linvA;
            int2 hi, lo;
            hi.x = pack2(w0, w1); hi.y = pack2(w2, w3);
            lo.x = pack2(w0 - bf2f(f2bf(w0)), w1 - bf2f(f2bf(w1)));
            lo.y = pack2(w2 - bf2f(f2bf(w2)), w3 - bf2f(f2bf(w3)));
            *(int2*)(Ahi + rowA + mt * 16 + quad * 4) = hi;
            *(int2*)(Alo + rowA + mt * 16 + quad * 4) = lo;
            w0 = (oB[mt][0] + o2B[0]) * linvB;
            w1 = (oB[mt][1] + o2B[1]) * linvB;
            w2 = (oB[mt][2] + o2B[2]) * linvB;
            w3 = (oB[mt][3] + o2B[3]) * linvB;
            hi.x = pack2(w0, w1); hi.y = pack2(w2, w3);
            lo.x = pack2(w0 - bf2f(f2bf(w0)), w1 - bf2f(f2bf(w1)));
            lo.y = pack2(w2 - bf2f(f2bf(w2)), w3 - bf2f(f2bf(w3)));
            *(int2*)(Ahi + rowB + mt * 16 + quad * 4) = hi;
            *(int2*)(Alo + rowB + mt * 16 + quad * 4) = lo;
        }
    }
    #undef KOFF
    #undef VOFF
}

// ---------------------------------------------------------------- out GEMM
__global__ __launch_bounds__(256) void out_gemm(
    const short* __restrict__ Ahi, const short* __restrict__ Alo,
    const short* __restrict__ Whi, const short* __restrict__ Wlo,
    const float* __restrict__ bo, float* __restrict__ Out)
{
    __shared__ short SMEM[24576];                 // 48 KB
    #define AHS(bf) (SMEM + (bf) * 4096)
    #define ALS(bf) (SMEM + 8192 + (bf) * 4096)
    #define BHS(bf) (SMEM + 16384 + (bf) * 2048)
    #define BLS(bf) (SMEM + 20480 + (bf) * 2048)
    const int lane = threadIdx.x & 63, wave = threadIdx.x >> 6;
    const int col = lane & 15, quad = lane >> 4;
    const int wm = wave & 1, wn = wave >> 1;
    const int m0 = blockIdx.x * 128;
    const int n0 = blockIdx.y * 64;

    const int rl = lane >> 2, pch = lane & 3;
    const int lch = pch ^ (rl & 3) ^ ((rl >> 2) & 3);
    const int seg = wave * 2;
    const short* ah0 = Ahi + (size_t)(m0 + seg * 16 + rl) * 512 + lch * 8;
    const short* ah1 = ah0 + (size_t)16 * 512;
    const short* al0 = Alo + (size_t)(m0 + seg * 16 + rl) * 512 + lch * 8;
    const short* al1 = al0 + (size_t)16 * 512;
    const short* bh0 = Whi + (size_t)(n0 + wave * 16 + rl) * 512 + lch * 8;
    const short* bl0 = Wlo + (size_t)(n0 + wave * 16 + rl) * 512 + lch * 8;

    floatx4 acc[4][2] = {};

    GLDS16(ah0, AHS(0) + seg * 512);
    GLDS16(ah1, AHS(0) + (seg + 1) * 512);
    GLDS16(al0, ALS(0) + seg * 512);
    GLDS16(al1, ALS(0) + (seg + 1) * 512);
    GLDS16(bh0, BHS(0) + wave * 512);
    GLDS16(bl0, BLS(0) + wave * 512);
    __syncthreads();

    for (int t = 0; t < 16; ++t) {
        const int cur = t & 1;
        if (t < 15) {
            const int kb = (t + 1) * 32;
            GLDS16(ah0 + kb, AHS(cur ^ 1) + seg * 512);
            GLDS16(ah1 + kb, AHS(cur ^ 1) + (seg + 1) * 512);
            GLDS16(al0 + kb, ALS(cur ^ 1) + seg * 512);
            GLDS16(al1 + kb, ALS(cur ^ 1) + (seg + 1) * 512);
            GLDS16(bh0 + kb, BHS(cur ^ 1) + wave * 512);
            GLDS16(bl0 + kb, BLS(cur ^ 1) + wave * 512);
        }
        short8 ahf[4], alf[4], bhf[2], blf[2];
        #pragma unroll
        for (int it = 0; it < 4; ++it) {
            const int rA = wm * 64 + it * 16 + col;
            const int pA = quad ^ (rA & 3) ^ ((rA >> 2) & 3);
            ahf[it] = *(const short8*)(AHS(cur) + rA * 32 + pA * 8);
            alf[it] = *(const short8*)(ALS(cur) + rA * 32 + pA * 8);
        }
        #pragma unroll
        for (int jt = 0; jt < 2; ++jt) {
            const int rB = wn * 32 + jt * 16 + col;
            const int pB = quad ^ (rB & 3) ^ ((rB >> 2) & 3);
            bhf[jt] = *(const short8*)(BHS(cur) + rB * 32 + pB * 8);
            blf[jt] = *(const short8*)(BLS(cur) + rB * 32 + pB * 8);
        }
        #pragma unroll
        for (int i = 0; i < 4; ++i)
            #pragma unroll
            for (int j = 0; j < 2; ++j) {
                acc[i][j] = MFMA(ahf[i], bhf[j], acc[i][j]);
                acc[i][j] = MFMA(ahf[i], blf[j], acc[i][j]);
                acc[i][j] = MFMA(alf[i], bhf[j], acc[i][j]);
            }
        __syncthreads();
    }

    #pragma unroll
    for (int i = 0; i < 4; ++i)
        #pragma unroll
        for (int j = 0; j < 2; ++j)
            #pragma unroll
            for (int r = 0; r < 4; ++r) {
                int m = m0 + wm * 64 + i * 16 + quad * 4 + r;
                int n = n0 + wn * 32 + j * 16 + col;
                Out[(size_t)m * 512 + n] = acc[i][j][r] + bo[n];
            }
    #undef AHS
    #undef ALS
    #undef BHS
    #undef BLS
}

// ---------------------------------------------------------------- launcher
extern "C" void kernel_launch(void* const* d_in, const int* in_sizes, int n_in,
                              void* d_out, int out_size, void* d_ws, size_t ws_size,
                              hipStream_t stream) {
    (void)in_sizes; (void)n_in; (void)out_size; (void)ws_size;
    const float* x   = (const float*)d_in[0];
    const float* W_q = (const float*)d_in[1];
    const float* b_q = (const float*)d_in[2];
    const float* W_k = (const float*)d_in[3];
    const float* b_k = (const float*)d_in[4];
    const float* W_v = (const float*)d_in[5];
    const float* b_v = (const float*)d_in[6];
    const float* W_o = (const float*)d_in[7];
    const float* b_o = (const float*)d_in[8];
    float* out = (float*)d_out;
    char* ws = (char*)d_ws;

    short* Xb   = (short*)(ws + 0);          // 8192*512*2  = 8,388,608
    short* Wqb  = (short*)(ws + 8388608);
    short* Wkb  = (short*)(ws + 8912896);
    short* Wvb  = (short*)(ws + 9437184);
    short* Wohi = (short*)(ws + 9961472);
    short* Wolo = (short*)(ws + 10485760);
    short* Qb   = (short*)(ws + 11010048);   // [16][4096][64]
    short* Kb   = (short*)(ws + 19398656);
    short* VTb  = (short*)(ws + 27787264);   // [16][64][4096]
    short* Ahi  = (short*)(ws + 36175872);   // [8192][512]
    short* Alo  = (short*)(ws + 44564480);   // end 52,953,088 bytes

    cvt_bf16<<<dim3(2048), dim3(256), 0, stream>>>(x, Xb, 4194304);
    cvt3_bf16<<<dim3(384), dim3(256), 0, stream>>>(W_q, W_k, W_v, Wqb, Wkb, Wvb);
    cvt_split<<<dim3(128), dim3(256), 0, stream>>>(W_o, Wohi, Wolo, 262144);
    qkv_gemm<<<dim3(64, 12), dim3(256), 0, stream>>>(Xb, Wqb, Wkb, Wvb, b_q, b_k, b_v, Qb, Kb, VTb);
    flash_attn<<<dim3(512), dim3(512), 0, stream>>>(Qb, Kb, VTb, Ahi, Alo);
    out_gemm<<<dim3(64, 8), dim3(256), 0, stream>>>(Ahi, Alo, Wohi, Wolo, b_o, out);
}

// Round 3
// 212.779 us; speedup vs baseline: 1.1315x; 1.0859x over previous
//
#include <hip/hip_runtime.h>
#include <hip/hip_bf16.h>
#include <stdint.h>

// MultiheadSelfAttention: B=2, S=4096, D=512, H=8, HD=64
// v12: VALU diet on the softmax chain.
//  (1) exp2f -> raw v_exp_f32 (__builtin_amdgcn_exp2f): drops OCML's
//      denorm/range fixup VALU ops; our domain sa<=0 is exactly handled
//      (underflow -> 0 is the correct P contribution).
//  (2) s_setprio(1) around QK^T and PV MFMA clusters (T5): lets waves in
//      the exp phase yield issue slots to MFMA-ready waves.
// Everything else identical to v11b (16x16x16 PV MFMA, no P-transpose).

typedef __attribute__((ext_vector_type(8))) short short8;
typedef __attribute__((ext_vector_type(4))) short sv4;
typedef __attribute__((ext_vector_type(4))) float floatx4;

#define MFMA(a, b, c) __builtin_amdgcn_mfma_f32_16x16x32_bf16((a), (b), (c), 0, 0, 0)

__device__ __forceinline__ floatx4 MFMA16(sv4 a, sv4 b, floatx4 c) {
#if __has_builtin(__builtin_amdgcn_mfma_f32_16x16x16bf16_1k)
    return __builtin_amdgcn_mfma_f32_16x16x16bf16_1k(a, b, c, 0, 0, 0);
#elif __has_builtin(__builtin_amdgcn_mfma_f32_16x16x16_bf16)
    return __builtin_amdgcn_mfma_f32_16x16x16_bf16(a, b, c, 0, 0, 0);
#else
    floatx4 d;
    asm volatile("v_mfma_f32_16x16x16_bf16 %0, %1, %2, %3"
                 : "=v"(d) : "v"(a), "v"(b), "v"(c));
    return d;
#endif
}

typedef __attribute__((address_space(1))) const void* gas_t;
typedef __attribute__((address_space(3))) void* las_t;
#define GLDS16(g, l) __builtin_amdgcn_global_load_lds((gas_t)(g), (las_t)(l), 16, 0, 0)

#define SM_SHIFT 13.0f

__device__ __forceinline__ float fexp2(float x) {
#if __has_builtin(__builtin_amdgcn_exp2f)
    return __builtin_amdgcn_exp2f(x);      // bare v_exp_f32
#else
    float r;
    asm("v_exp_f32 %0, %1" : "=v"(r) : "v"(x));
    return r;
#endif
}

__device__ __forceinline__ short f2bf(float f) {
    union { float f; uint32_t u; } c; c.f = f;
    uint32_t u = c.u;
    u += 0x7fffu + ((u >> 16) & 1u);   // RNE
    return (short)(u >> 16);
}
__device__ __forceinline__ float bf2f(short s) {
    union { float f; uint32_t u; } c; c.u = ((uint32_t)(uint16_t)s) << 16;
    return c.f;
}
__device__ __forceinline__ int pack2(float a, float b) {
    return (int)(uint16_t)f2bf(a) | ((int)(uint16_t)f2bf(b) << 16);
}
// bf16 pack of two floats: 1 instr on gfx950 if builtin exists, else 3.
__device__ __forceinline__ int pack2rn(float a, float b) {
#if __has_builtin(__builtin_amdgcn_cvt_pk_bf16_f32)
    auto r = __builtin_amdgcn_cvt_pk_bf16_f32(a, b);
    int out; __builtin_memcpy(&out, &r, 4);
    return out;
#else
    union { float f; uint32_t u; } x, y; x.f = a; y.f = b;
    return __builtin_amdgcn_perm(y.u + 0x8000u, x.u + 0x8000u, 0x07060302);
#endif
}

// ---------------------------------------------------------------- converts
__global__ void cvt_bf16(const float* __restrict__ src, short* __restrict__ dst, int n) {
    int i = (blockIdx.x * 256 + threadIdx.x) * 8;
    if (i >= n) return;
    floatx4 v0 = *(const floatx4*)(src + i);
    floatx4 v1 = *(const floatx4*)(src + i + 4);
    short8 o;
    #pragma unroll
    for (int j = 0; j < 4; ++j) { o[j] = f2bf(v0[j]); o[4 + j] = f2bf(v1[j]); }
    *(short8*)(dst + i) = o;
}

__global__ void cvt3_bf16(const float* __restrict__ s0, const float* __restrict__ s1,
                          const float* __restrict__ s2, short* __restrict__ d0,
                          short* __restrict__ d1, short* __restrict__ d2) {
    int idx = blockIdx.x * 256 + threadIdx.x;
    int which = idx >> 15;
    int i = (idx & 32767) * 8;
    const float* src = which == 0 ? s0 : which == 1 ? s1 : s2;
    short* dst = which == 0 ? d0 : which == 1 ? d1 : d2;
    floatx4 v0 = *(const floatx4*)(src + i);
    floatx4 v1 = *(const floatx4*)(src + i + 4);
    short8 o;
    #pragma unroll
    for (int j = 0; j < 4; ++j) { o[j] = f2bf(v0[j]); o[4 + j] = f2bf(v1[j]); }
    *(short8*)(dst + i) = o;
}

__global__ void cvt_split(const float* __restrict__ src, short* __restrict__ hi,
                          short* __restrict__ lo, int n) {
    int i = (blockIdx.x * 256 + threadIdx.x) * 8;
    if (i >= n) return;
    floatx4 v0 = *(const floatx4*)(src + i);
    floatx4 v1 = *(const floatx4*)(src + i + 4);
    short8 h, l;
    #pragma unroll
    for (int j = 0; j < 4; ++j) {
        short hh = f2bf(v0[j]); h[j] = hh; l[j] = f2bf(v0[j] - bf2f(hh));
        short hh1 = f2bf(v1[j]); h[4 + j] = hh1; l[4 + j] = f2bf(v1[j] - bf2f(hh1));
    }
    *(short8*)(hi + i) = h;
    *(short8*)(lo + i) = l;
}

// ---------------------------------------------------------------- QKV GEMM
__global__ __launch_bounds__(256) void qkv_gemm(
    const short* __restrict__ Xb,
    const short* __restrict__ Wq, const short* __restrict__ Wk, const short* __restrict__ Wv,
    const float* __restrict__ bq, const float* __restrict__ bk, const float* __restrict__ bv,
    short* __restrict__ Qo, short* __restrict__ Ko, short* __restrict__ VTo)
{
    __shared__ short SMEM[16384];                 // 32 KB
    #define ASH(bf) (SMEM + (bf) * 4096)
    #define BSH(bf) (SMEM + 8192 + (bf) * 4096)
    const int lane = threadIdx.x & 63, wave = threadIdx.x >> 6;
    const int col = lane & 15, quad = lane >> 4;
    const int wm = wave & 1, wn = wave >> 1;
    const int m0 = blockIdx.x * 128;
    const int by = blockIdx.y;
    const int which = by >> 2;                    // 0=Q,1=K,2=V
    const int n0 = (by & 3) * 128;
    const short* W = which == 0 ? Wq : which == 1 ? Wk : Wv;
    const float* bias = which == 0 ? bq : which == 1 ? bk : bv;
    const float oscale = which == 0 ? 0.1803368801111204f : 1.0f;  // 0.125*log2e

    const int rl = lane >> 2, pch = lane & 3;
    const int lch = pch ^ (rl & 3) ^ ((rl >> 2) & 3);
    const int seg = wave * 2;
    const short* ag0 = Xb + (size_t)(m0 + seg * 16 + rl) * 512 + lch * 8;
    const short* ag1 = ag0 + (size_t)16 * 512;
    const short* bg0 = W + (size_t)(n0 + seg * 16 + rl) * 512 + lch * 8;
    const short* bg1 = bg0 + (size_t)16 * 512;

    floatx4 acc[4][4] = {};

    GLDS16(ag0, ASH(0) + seg * 512);
    GLDS16(ag1, ASH(0) + (seg + 1) * 512);
    GLDS16(bg0, BSH(0) + seg * 512);
    GLDS16(bg1, BSH(0) + (seg + 1) * 512);
    __syncthreads();

    for (int t = 0; t < 16; ++t) {
        const int cur = t & 1;
        if (t < 15) {
            const int kb = (t + 1) * 32;
            GLDS16(ag0 + kb, ASH(cur ^ 1) + seg * 512);
            GLDS16(ag1 + kb, ASH(cur ^ 1) + (seg + 1) * 512);
            GLDS16(bg0 + kb, BSH(cur ^ 1) + seg * 512);
            GLDS16(bg1 + kb, BSH(cur ^ 1) + (seg + 1) * 512);
        }
        short8 af[4], bf[4];
        #pragma unroll
        for (int it = 0; it < 4; ++it) {
            const int rA = wm * 64 + it * 16 + col;
            const int pA = quad ^ (rA & 3) ^ ((rA >> 2) & 3);
            af[it] = *(const short8*)(ASH(cur) + rA * 32 + pA * 8);
            const int rB = wn * 64 + it * 16 + col;
            const int pB = quad ^ (rB & 3) ^ ((rB >> 2) & 3);
            bf[it] = *(const short8*)(BSH(cur) + rB * 32 + pB * 8);
        }
        #pragma unroll
        for (int i = 0; i < 4; ++i)
            #pragma unroll
            for (int j = 0; j < 4; ++j)
                acc[i][j] = MFMA(af[i], bf[j], acc[i][j]);
        __syncthreads();
    }

    if (which < 2) {
        #pragma unroll
        for (int i = 0; i < 4; ++i)
            #pragma unroll
            for (int j = 0; j < 4; ++j)
                #pragma unroll
                for (int r = 0; r < 4; ++r) {
                    int m = m0 + wm * 64 + i * 16 + quad * 4 + r;
                    int n = n0 + wn * 64 + j * 16 + col;
                    float v = (acc[i][j][r] + bias[n]) * oscale;
                    int b = m >> 12, s = m & 4095;
                    int h = n >> 6, hd = n & 63;
                    int bh = b * 8 + h;
                    short bv16 = f2bf(v);
                    if (which == 0) Qo[((size_t)bh * 4096 + s) * 64 + hd] = bv16;
                    else            Ko[((size_t)bh * 4096 + s) * 64 + hd] = bv16;
                }
    } else {
        // V: per-wave LDS transpose (post-barrier, staging LDS is dead)
        short* tb = SMEM + wave * 4096;
        #pragma unroll
        for (int n2 = 0; n2 < 2; ++n2) {
            #pragma unroll
            for (int jj = 0; jj < 2; ++jj) {
                const int j = n2 * 2 + jj;
                const int n_rel = jj * 16 + col;
                const float bv_ = bias[n0 + wn * 64 + j * 16 + col];
                #pragma unroll
                for (int i = 0; i < 4; ++i) {
                    const int m_rel = i * 16 + quad * 4;
                    *(int*)(tb + n_rel * 72 + m_rel) =
                        pack2(acc[i][j][0] + bv_, acc[i][j][1] + bv_);
                    *(int*)(tb + n_rel * 72 + m_rel + 2) =
                        pack2(acc[i][j][2] + bv_, acc[i][j][3] + bv_);
                }
            }
            asm volatile("s_waitcnt lgkmcnt(0)" ::: "memory");  // wave-local
            const int n_rel = lane & 31, half = lane >> 5;
            const int n = n0 + wn * 64 + n2 * 32 + n_rel;
            const int h = n >> 6, hd = n & 63;
            const int bh = (m0 >> 12) * 8 + h;
            const int s0 = (m0 & 4095) + wm * 64 + half * 32;
            const short* src = tb + n_rel * 72 + half * 32;
            short* dst = VTo + ((size_t)bh * 64 + hd) * 4096 + s0;
            #pragma unroll
            for (int c = 0; c < 4; ++c)
                *(int4*)(dst + c * 8) = *(const int4*)(src + c * 8);
        }
    }
    #undef ASH
    #undef BSH
}

// ---------------------------------------------------------------- flash attn
// Fixed-shift softmax; shift pre-folded into sa (QK^T seeded with C=-13).
// P packed to bf16 pairs feeds the 16x16x16 PV MFMA's B-operand DIRECTLY
// (both use k = quad*4+j grouping) -- no lane exchange. l accumulated via
// ones-MFMA on the same fragments.
__device__ __forceinline__ void softmax_pk(
    const floatx4* sa, floatx4& lacc, sv4 ones1, sv4* pb)
{
    #pragma unroll
    for (int nt = 0; nt < 4; ++nt) {
        float p0 = fexp2(sa[nt][0]);
        float p1 = fexp2(sa[nt][1]);
        float p2 = fexp2(sa[nt][2]);
        float p3 = fexp2(sa[nt][3]);
        union { int i[2]; sv4 s; } u;
        u.i[0] = pack2rn(p0, p1);
        u.i[1] = pack2rn(p2, p3);
        pb[nt] = u.s;
        lacc = MFMA16(ones1, u.s, lacc);   // l += column sums of this 16-k block
    }
}

__global__ __launch_bounds__(512, 4) void flash_attn(
    const short* __restrict__ Q, const short* __restrict__ Kk,
    const short* __restrict__ VT,
    short* __restrict__ Ahi, short* __restrict__ Alo)
{
    __shared__ float SMEMf[16384];               // 64 KB
    short* SMEM = (short*)SMEMf;
    const int lane = threadIdx.x & 63, wave = threadIdx.x >> 6;
    const int col = lane & 15, quad = lane >> 4;
    const int id = blockIdx.x;
    const int bh = (id & 7) * 2 + (id >> 8);     // 2 bh per XCD cluster
    const int bx = (id >> 3) & 31;
    const int b = bh >> 3, h = bh & 7;
    const int qw = wave & 3, kz = wave >> 2;
    const int q0 = bx * 128 + qw * 32;
    const int kbeg = kz * 2048;
    const size_t base = (size_t)bh * 4096 * 64;
    const size_t vbase = (size_t)bh * 64 * 4096;

    #define KOFF(z, f) (((z) * 2 + (f)) * 4096)
    #define VOFF(z, f) (16384 + ((z) * 2 + (f)) * 4096)

    const short* qptr = Q + base + (size_t)(q0 + col) * 64 + quad * 8;
    short8 qA0 = *(const short8*)(qptr);
    short8 qA1 = *(const short8*)(qptr + 32);
    short8 qB0 = *(const short8*)(qptr + 16 * 64);
    short8 qB1 = *(const short8*)(qptr + 16 * 64 + 32);

    const int rloc = lane >> 3, pch = lane & 7;
    const int lch = pch ^ rloc;
    const short* kst0 = Kk + base + (size_t)(kbeg + qw * 16 + rloc) * 64 + lch * 8;
    const short* kst1 = kst0 + (size_t)8 * 64;
    const short* vst0 = VT + vbase + (size_t)(qw * 16 + rloc) * 4096 + kbeg + lch * 8;
    const short* vst1 = vst0 + (size_t)8 * 4096;

    floatx4 oA[4] = {}, oB[4] = {};
    floatx4 laccA = {0.f, 0.f, 0.f, 0.f}, laccB = {0.f, 0.f, 0.f, 0.f};
    const floatx4 mshift = {-SM_SHIFT, -SM_SHIFT, -SM_SHIFT, -SM_SHIFT};
    sv4 ones1;
    #pragma unroll
    for (int j = 0; j < 4; ++j) ones1[j] = (short)0x3F80;   // bf16 1.0

    const int sw = col & 7;
    const int co0 = (quad ^ sw) * 8;
    const int co1 = ((quad + 4) ^ sw) * 8;
    // V fragment offsets for 16x16x16 PV: logical elem = nt*16 + quad*4;
    // 16B-chunk swizzle c_phys = c_log ^ (row&7), row&7 == col&7 == sw.
    int voff[4];
    #pragma unroll
    for (int nt = 0; nt < 4; ++nt)
        voff[nt] = ((2 * nt + (quad >> 1)) ^ sw) * 8 + (quad & 1) * 4;

    {
        short* kl = SMEM + KOFF(kz, 0) + (qw * 16) * 64;
        short* vl = SMEM + VOFF(kz, 0) + (qw * 16) * 64;
        GLDS16(kst0, kl);
        GLDS16(kst1, kl + 8 * 64);
        GLDS16(vst0, vl);
        GLDS16(vst1, vl + 8 * 64);
    }
    __syncthreads();

    for (int t = 0; t < 32; ++t) {
        const int cur = t & 1;
        if (t < 31) {
            const int kk2 = (t + 1) * 64;
            short* kl = SMEM + KOFF(kz, cur ^ 1) + (qw * 16) * 64;
            short* vl = SMEM + VOFF(kz, cur ^ 1) + (qw * 16) * 64;
            GLDS16(kst0 + (size_t)kk2 * 64, kl);
            GLDS16(kst1 + (size_t)kk2 * 64, kl + 8 * 64);
            GLDS16(vst0 + kk2, vl);
            GLDS16(vst1 + kk2, vl + 8 * 64);
        }
        floatx4 saA[4], saB[4];
        __builtin_amdgcn_s_setprio(1);
        #pragma unroll
        for (int nt = 0; nt < 4; ++nt) {
            const short* kr = SMEM + KOFF(kz, cur) + (nt * 16 + col) * 64;
            short8 k0 = *(const short8*)(kr + co0);
            short8 k1 = *(const short8*)(kr + co1);
            floatx4 z = MFMA(k0, qA0, mshift);       // seed C=-13: sa = S~ - 13
            saA[nt] = MFMA(k1, qA1, z);
            floatx4 z2 = MFMA(k0, qB0, mshift);
            saB[nt] = MFMA(k1, qB1, z2);
        }
        __builtin_amdgcn_s_setprio(0);
        sv4 pbA[4], pbB[4];
        softmax_pk(saA, laccA, ones1, pbA);
        softmax_pk(saB, laccB, ones1, pbB);
        __builtin_amdgcn_s_setprio(1);
        #pragma unroll
        for (int mt = 0; mt < 4; ++mt) {
            const short* vr = SMEM + VOFF(kz, cur) + (mt * 16 + col) * 64;
            #pragma unroll
            for (int nt = 0; nt < 4; ++nt) {
                const sv4 v = *(const sv4*)(vr + voff[nt]);
                oA[mt] = MFMA16(v, pbA[nt], oA[mt]);
                oB[mt] = MFMA16(v, pbB[nt], oB[mt]);
            }
        }
        __builtin_amdgcn_s_setprio(0);
        __syncthreads();
    }

    float lA = laccA[0], lB = laccB[0];   // quad-uniform (full chunk sums)

    // ---- split-K merge: same fixed shift on both halves -> pure add
    float* Osh = SMEMf;
    float* Msh = SMEMf + 8704;   // reused for l
    if (kz == 1) {
        #pragma unroll
        for (int mt = 0; mt < 4; ++mt) {
            *(floatx4*)&Osh[(qw * 2 + 0) * 1088 + col * 68 + mt * 16 + quad * 4] = oA[mt];
            *(floatx4*)&Osh[(qw * 2 + 1) * 1088 + col * 68 + mt * 16 + quad * 4] = oB[mt];
        }
        if (quad == 0) {
            Msh[qw * 32 + col] = lA;
            Msh[qw * 32 + col + 16] = lB;
        }
    }
    __syncthreads();
    if (kz == 0) {
        float linvA = 1.0f / (lA + Msh[qw * 32 + col]);
        float linvB = 1.0f / (lB + Msh[qw * 32 + col + 16]);
        size_t rowA = (size_t)(b * 4096 + q0 + col) * 512 + h * 64;
        size_t rowB = rowA + (size_t)16 * 512;
        #pragma unroll
        for (int mt = 0; mt < 4; ++mt) {
            floatx4 o2A = *(const floatx4*)&Osh[(qw * 2 + 0) * 1088 + col * 68 + mt * 16 + quad * 4];
            floatx4 o2B = *(const floatx4*)&Osh[(qw * 2 + 1) * 1088 + col * 68 + mt * 16 + quad * 4];
            float w0 = (oA[mt][0] + o2A[0]) * linvA;
            float w1 = (oA[mt][1] + o2A[1]) * linvA;
            float w2 = (oA[mt][2] + o2A[2]) * linvA;
            float w3 = (oA[mt][3] + o2A[3]) * linvA;
            int2 hi, lo;
            hi.x = pack2(w0, w1); hi.y = pack2(w2, w3);
            lo.x = pack2(w0 - bf2f(f2bf(w0)), w1 - bf2f(f2bf(w1)));
            lo.y = pack2(w2 - bf2f(f2bf(w2)), w3 - bf2f(f2bf(w3)));
            *(int2*)(Ahi + rowA + mt * 16 + quad * 4) = hi;
            *(int2*)(Alo + rowA + mt * 16 + quad * 4) = lo;
            w0 = (oB[mt][0] + o2B[0]) * linvB;
            w1 = (oB[mt][1] + o2B[1]) * linvB;
            w2 = (oB[mt][2] + o2B[2]) * linvB;
            w3 = (oB[mt][3] + o2B[3]) * linvB;
            hi.x = pack2(w0, w1); hi.y = pack2(w2, w3);
            lo.x = pack2(w0 - bf2f(f2bf(w0)), w1 - bf2f(f2bf(w1)));
            lo.y = pack2(w2 - bf2f(f2bf(w2)), w3 - bf2f(f2bf(w3)));
            *(int2*)(Ahi + rowB + mt * 16 + quad * 4) = hi;
            *(int2*)(Alo + rowB + mt * 16 + quad * 4) = lo;
        }
    }
    #undef KOFF
    #undef VOFF
}

// ---------------------------------------------------------------- out GEMM
__global__ __launch_bounds__(256) void out_gemm(
    const short* __restrict__ Ahi, const short* __restrict__ Alo,
    const short* __restrict__ Whi, const short* __restrict__ Wlo,
    const float* __restrict__ bo, float* __restrict__ Out)
{
    __shared__ short SMEM[24576];                 // 48 KB
    #define AHS(bf) (SMEM + (bf) * 4096)
    #define ALS(bf) (SMEM + 8192 + (bf) * 4096)
    #define BHS(bf) (SMEM + 16384 + (bf) * 2048)
    #define BLS(bf) (SMEM + 20480 + (bf) * 2048)
    const int lane = threadIdx.x & 63, wave = threadIdx.x >> 6;
    const int col = lane & 15, quad = lane >> 4;
    const int wm = wave & 1, wn = wave >> 1;
    const int m0 = blockIdx.x * 128;
    const int n0 = blockIdx.y * 64;

    const int rl = lane >> 2, pch = lane & 3;
    const int lch = pch ^ (rl & 3) ^ ((rl >> 2) & 3);
    const int seg = wave * 2;
    const short* ah0 = Ahi + (size_t)(m0 + seg * 16 + rl) * 512 + lch * 8;
    const short* ah1 = ah0 + (size_t)16 * 512;
    const short* al0 = Alo + (size_t)(m0 + seg * 16 + rl) * 512 + lch * 8;
    const short* al1 = al0 + (size_t)16 * 512;
    const short* bh0 = Whi + (size_t)(n0 + wave * 16 + rl) * 512 + lch * 8;
    const short* bl0 = Wlo + (size_t)(n0 + wave * 16 + rl) * 512 + lch * 8;

    floatx4 acc[4][2] = {};

    GLDS16(ah0, AHS(0) + seg * 512);
    GLDS16(ah1, AHS(0) + (seg + 1) * 512);
    GLDS16(al0, ALS(0) + seg * 512);
    GLDS16(al1, ALS(0) + (seg + 1) * 512);
    GLDS16(bh0, BHS(0) + wave * 512);
    GLDS16(bl0, BLS(0) + wave * 512);
    __syncthreads();

    for (int t = 0; t < 16; ++t) {
        const int cur = t & 1;
        if (t < 15) {
            const int kb = (t + 1) * 32;
            GLDS16(ah0 + kb, AHS(cur ^ 1) + seg * 512);
            GLDS16(ah1 + kb, AHS(cur ^ 1) + (seg + 1) * 512);
            GLDS16(al0 + kb, ALS(cur ^ 1) + seg * 512);
            GLDS16(al1 + kb, ALS(cur ^ 1) + (seg + 1) * 512);
            GLDS16(bh0 + kb, BHS(cur ^ 1) + wave * 512);
            GLDS16(bl0 + kb, BLS(cur ^ 1) + wave * 512);
        }
        short8 ahf[4], alf[4], bhf[2], blf[2];
        #pragma unroll
        for (int it = 0; it < 4; ++it) {
            const int rA = wm * 64 + it * 16 + col;
            const int pA = quad ^ (rA & 3) ^ ((rA >> 2) & 3);
            ahf[it] = *(const short8*)(AHS(cur) + rA * 32 + pA * 8);
            alf[it] = *(const short8*)(ALS(cur) + rA * 32 + pA * 8);
        }
        #pragma unroll
        for (int jt = 0; jt < 2; ++jt) {
            const int rB = wn * 32 + jt * 16 + col;
            const int pB = quad ^ (rB & 3) ^ ((rB >> 2) & 3);
            bhf[jt] = *(const short8*)(BHS(cur) + rB * 32 + pB * 8);
            blf[jt] = *(const short8*)(BLS(cur) + rB * 32 + pB * 8);
        }
        #pragma unroll
        for (int i = 0; i < 4; ++i)
            #pragma unroll
            for (int j = 0; j < 2; ++j) {
                acc[i][j] = MFMA(ahf[i], bhf[j], acc[i][j]);
                acc[i][j] = MFMA(ahf[i], blf[j], acc[i][j]);
                acc[i][j] = MFMA(alf[i], bhf[j], acc[i][j]);
            }
        __syncthreads();
    }

    #pragma unroll
    for (int i = 0; i < 4; ++i)
        #pragma unroll
        for (int j = 0; j < 2; ++j)
            #pragma unroll
            for (int r = 0; r < 4; ++r) {
                int m = m0 + wm * 64 + i * 16 + quad * 4 + r;
                int n = n0 + wn * 32 + j * 16 + col;
                Out[(size_t)m * 512 + n] = acc[i][j][r] + bo[n];
            }
    #undef AHS
    #undef ALS
    #undef BHS
    #undef BLS
}

// ---------------------------------------------------------------- launcher
extern "C" void kernel_launch(void* const* d_in, const int* in_sizes, int n_in,
                              void* d_out, int out_size, void* d_ws, size_t ws_size,
                              hipStream_t stream) {
    (void)in_sizes; (void)n_in; (void)out_size; (void)ws_size;
    const float* x   = (const float*)d_in[0];
    const float* W_q = (const float*)d_in[1];
    const float* b_q = (const float*)d_in[2];
    const float* W_k = (const float*)d_in[3];
    const float* b_k = (const float*)d_in[4];
    const float* W_v = (const float*)d_in[5];
    const float* b_v = (const float*)d_in[6];
    const float* W_o = (const float*)d_in[7];
    const float* b_o = (const float*)d_in[8];
    float* out = (float*)d_out;
    char* ws = (char*)d_ws;

    short* Xb   = (short*)(ws + 0);          // 8192*512*2  = 8,388,608
    short* Wqb  = (short*)(ws + 8388608);
    short* Wkb  = (short*)(ws + 8912896);
    short* Wvb  = (short*)(ws + 9437184);
    short* Wohi = (short*)(ws + 9961472);
    short* Wolo = (short*)(ws + 10485760);
    short* Qb   = (short*)(ws + 11010048);   // [16][4096][64]
    short* Kb   = (short*)(ws + 19398656);
    short* VTb  = (short*)(ws + 27787264);   // [16][64][4096]
    short* Ahi  = (short*)(ws + 36175872);   // [8192][512]
    short* Alo  = (short*)(ws + 44564480);   // end 52,953,088 bytes

    cvt_bf16<<<dim3(2048), dim3(256), 0, stream>>>(x, Xb, 4194304);
    cvt3_bf16<<<dim3(384), dim3(256), 0, stream>>>(W_q, W_k, W_v, Wqb, Wkb, Wvb);
    cvt_split<<<dim3(128), dim3(256), 0, stream>>>(W_o, Wohi, Wolo, 262144);
    qkv_gemm<<<dim3(64, 12), dim3(256), 0, stream>>>(Xb, Wqb, Wkb, Wvb, b_q, b_k, b_v, Qb, Kb, VTb);
    flash_attn<<<dim3(512), dim3(512), 0, stream>>>(Qb, Kb, VTb, Ahi, Alo);
    out_gemm<<<dim3(64, 8), dim3(256), 0, stream>>>(Ahi, Alo, Wohi, Wolo, b_o, out);
}